// Round 15
// baseline (157.520 us; speedup 1.0000x reference)
//
#include <hip/hip_runtime.h>
#include <hip/hip_bf16.h>

#define NB 4
#define NT 2048
#define NS 2048
#define ND 1024
#define NH 16

typedef __attribute__((ext_vector_type(8))) __bf16 bf16x8;
typedef __attribute__((ext_vector_type(4))) __bf16 bf16x4;
typedef __attribute__((ext_vector_type(2))) __bf16 bf16x2;
typedef __attribute__((ext_vector_type(4))) float f32x4;
typedef __attribute__((ext_vector_type(16))) float f32x16;

__device__ __forceinline__ void load_lds16(const void* g, void* l) {
  __builtin_amdgcn_global_load_lds(
      (const __attribute__((address_space(1))) unsigned int*)g,
      (__attribute__((address_space(3))) unsigned int*)l, 16, 0, 0);
}

__device__ __forceinline__ unsigned pkbf(float lo, float hi) {
  bf16x2 t = {(__bf16)lo, (__bf16)hi};
  return __builtin_bit_cast(unsigned, t);
}

__device__ __forceinline__ f32x16 zero16() {
  f32x16 z;
#pragma unroll
  for (int i = 0; i < 16; i++) z[i] = 0.f;
  return z;
}

// ---------------- Wq/Wk fp32 -> bf16 (small, 8MB read) ----------------
__global__ __launch_bounds__(256) void cvtw_kernel(const float* __restrict__ wq,
                                                   const float* __restrict__ wk,
                                                   __bf16* __restrict__ owq,
                                                   __bf16* __restrict__ owk) {
  int i = blockIdx.x * 256 + threadIdx.x;  // 0..524287 float4s
  const float* src = (i < 262144) ? wq : wk;
  __bf16* dst = (i < 262144) ? owq : owk;
  int off = i & 262143;
  float4 v = reinterpret_cast<const float4*>(src)[off];
  bf16x4 o = {(__bf16)v.x, (__bf16)v.y, (__bf16)v.z, (__bf16)v.w};
  reinterpret_cast<bf16x4*>(dst)[off] = o;
}

// ---------------- merged proj (blocks 0..1023) + V transpose (1024..3071) --------------
// proj: out = relu(X_f32 @ W_bf16^T + b) * scale  (R11 known-good structure).
// A: fp32 reg-staged 1-deep. W: bf16 gload_lds, single Bs buffer.
// Per iter VMEM issue: B_kt(2 gload_lds) -- asm pin -- A_next(4 loads);
// then vmcnt(4): with the order PINNED, this provably drains B_kt (oldest)
// and leaves only A_next in flight. (R13/R14's dbuf scheme raced because the
// compiler could permute issue order; the pin removes that freedom.)
__global__ __launch_bounds__(256) void projvt_kernel(const float* __restrict__ query,
                                                     const float* __restrict__ key,
                                                     const __bf16* __restrict__ Wqb,
                                                     const __bf16* __restrict__ Wkb,
                                                     const float* __restrict__ bq,
                                                     const float* __restrict__ bk,
                                                     __bf16* __restrict__ outq,
                                                     __bf16* __restrict__ outk,
                                                     const float* __restrict__ value,
                                                     __bf16* __restrict__ vt) {
  __shared__ __align__(16) char psm[16896];  // proj: As 8K + Bs 8K; vt: 64x65 f32
  const int tid = threadIdx.x;

  if (blockIdx.x >= 1024) {
    // ---- vt path: value[B,S,1024] -> vt[B*H][64][S]
    float (*tile)[65] = (float(*)[65])psm;
    int bid = blockIdx.x - 1024;
    int st = bid & 31;
    int bh = bid >> 5;
    int b = bh >> 4, h = bh & 15;
    int s0 = st * 64;
#pragma unroll
    for (int rr = 0; rr < 16; rr++) {
      int idx = rr * 256 + tid;
      int r = idx >> 6, c = idx & 63;
      tile[r][c] = value[(size_t)(b * NS + s0 + r) * 1024 + h * 64 + c];
    }
    __syncthreads();
    int d0 = tid >> 5;
    int sp = (tid & 31) * 2;
#pragma unroll
    for (int rr = 0; rr < 8; rr++) {
      int d = rr * 8 + d0;
      bf16x2 o = {(__bf16)tile[sp][d], (__bf16)tile[sp + 1][d]};
      *reinterpret_cast<bf16x2*>(vt + ((size_t)bh * 64 + d) * NS + s0 + sp) = o;
    }
    return;
  }

  // ---- proj path
  __bf16* As = (__bf16*)psm;
  __bf16* Bs = (__bf16*)(psm + 8192);
  const int z = blockIdx.x >> 9;
  const float* A32 = z ? key : query;
  const __bf16* W = z ? Wkb : Wqb;
  const float* bias = z ? bk : bq;
  __bf16* out = z ? outk : outq;
  const float scale = z ? 1.0f : 0.18033688f;  // q: 0.125 * log2(e)

  const int w = tid >> 6, lane = tid & 63;
  int orig = blockIdx.x & 511;
  int wgid = (orig & 7) * 64 + (orig >> 3);  // XCD swizzle
  const int m0 = (wgid >> 3) * 128;
  const int n0 = (wgid & 7) * 128;
  const int wm = w >> 1, wn = w & 1;

  f32x4 acc[4][4];
#pragma unroll
  for (int i = 0; i < 4; i++)
#pragma unroll
    for (int j = 0; j < 4; j++) acc[i][j] = (f32x4){0.f, 0.f, 0.f, 0.f};

  const int arow = lane >> 2;       // 0..15
  const int acol = (lane & 3) * 8;  // 0,8,16,24 (elems)
  const int fr = lane & 15, fg = lane >> 4;

  const float* ap0 = A32 + (size_t)(m0 + w * 32 + arow) * 1024 + acol;
  const float* ap1 = ap0 + 16 * 1024;
  const __bf16* wb0 = W + (size_t)(n0 + w * 32 + arow) * 1024 + acol;
  const __bf16* wb1 = wb0 + 16 * 1024;
  __bf16* asw0 = &As[(w * 32 + arow) * 32 + acol];
  __bf16* asw1 = asw0 + 16 * 32;
  __bf16* bsd0 = &Bs[(w * 32) * 32];
  __bf16* bsd1 = &Bs[(w * 32 + 16) * 32];

  float4 a00 = *(const float4*)(ap0), a01 = *(const float4*)(ap0 + 4);
  float4 a10 = *(const float4*)(ap1), a11 = *(const float4*)(ap1 + 4);

  for (int kt = 0; kt < 1024; kt += 32) {
    // cvt current A regs -> LDS (LDS free: barrier2 of prev iter)
    *reinterpret_cast<bf16x8*>(asw0) =
        (bf16x8){(__bf16)a00.x, (__bf16)a00.y, (__bf16)a00.z, (__bf16)a00.w,
                 (__bf16)a01.x, (__bf16)a01.y, (__bf16)a01.z, (__bf16)a01.w};
    *reinterpret_cast<bf16x8*>(asw1) =
        (bf16x8){(__bf16)a10.x, (__bf16)a10.y, (__bf16)a10.z, (__bf16)a10.w,
                 (__bf16)a11.x, (__bf16)a11.y, (__bf16)a11.z, (__bf16)a11.w};
    // B: direct global->LDS (2 ops) -- MUST be issued before the A prefetch
    load_lds16(wb0 + kt, bsd0);
    load_lds16(wb1 + kt, bsd1);
    asm volatile("" ::: "memory");  // pin issue order: B before A-next
    if (kt < 992) {
      a00 = *(const float4*)(ap0 + kt + 32);
      a01 = *(const float4*)(ap0 + kt + 36);
      a10 = *(const float4*)(ap1 + kt + 32);
      a11 = *(const float4*)(ap1 + kt + 36);
      // order pinned above -> the 4 newest are the A loads; drain B + older
      asm volatile("s_waitcnt vmcnt(4) lgkmcnt(0)" ::: "memory");
    } else {
      asm volatile("s_waitcnt vmcnt(0) lgkmcnt(0)" ::: "memory");
    }
    __builtin_amdgcn_s_barrier();
    asm volatile("" ::: "memory");

    bf16x8 af[4], bfr[4];
#pragma unroll
    for (int mi = 0; mi < 4; mi++)
      af[mi] = *reinterpret_cast<const bf16x8*>(&As[(wm * 64 + mi * 16 + fr) * 32 + fg * 8]);
#pragma unroll
    for (int ni = 0; ni < 4; ni++)
      bfr[ni] = *reinterpret_cast<const bf16x8*>(&Bs[(wn * 64 + ni * 16 + fr) * 32 + fg * 8]);
#pragma unroll
    for (int mi = 0; mi < 4; mi++)
#pragma unroll
      for (int ni = 0; ni < 4; ni++)
        acc[mi][ni] = __builtin_amdgcn_mfma_f32_16x16x32_bf16(af[mi], bfr[ni], acc[mi][ni], 0, 0, 0);

    asm volatile("" ::: "memory");
    __builtin_amdgcn_s_barrier();
  }

#pragma unroll
  for (int ni = 0; ni < 4; ni++) {
    int n = n0 + wn * 64 + ni * 16 + fr;
    float bv = bias[n];
    int h = n >> 6, d = n & 63;
#pragma unroll
    for (int mi = 0; mi < 4; mi++) {
#pragma unroll
      for (int i = 0; i < 4; i++) {
        int m = m0 + wm * 64 + mi * 16 + fg * 4 + i;
        int b = m >> 11, t = m & 2047;
        float v = acc[mi][ni][i] + bv;
        v = fmaxf(v, 0.f) * scale;
        out[(size_t)((b * NH + h) * NT + t) * 64 + d] = (__bf16)v;
      }
    }
  }
}

// ---------------- flash attention (4 waves x 32 q-rows) -- unchanged (best: 86.4us) ----
__global__ __launch_bounds__(256, 4) void attn_kernel(const __bf16* __restrict__ Q,
                                                      const __bf16* __restrict__ K,
                                                      const __bf16* __restrict__ Vt,
                                                      const unsigned char* __restrict__ mask,
                                                      float* __restrict__ out) {
  __shared__ __align__(16) char smem[32768];
  const int tid = threadIdx.x;
  const int w = tid >> 6, lane = tid & 63;
  int orig = blockIdx.x;
  int wgid = (orig & 7) * 128 + (orig >> 3);  // XCD swizzle: 8 bh per XCD
  const int qt = wgid & 15, bh = wgid >> 4;
  const int b = bh >> 4, h = bh & 15;
  const int q0 = qt * 128 + w * 32;
  const int ql = lane & 31, hi = lane >> 5;

  const __bf16* kb = K + (size_t)bh * NS * 64;
  const __bf16* vb = Vt + (size_t)bh * 64 * NS;
  const unsigned char* mb = mask + (size_t)b * NS;

  bool anyMask;
  {
    const uint4* mp4 = reinterpret_cast<const uint4*>(mb);
    uint4 a = mp4[lane * 2], c = mp4[lane * 2 + 1];
    unsigned acc = a.x | a.y | a.z | a.w | c.x | c.y | c.z | c.w;
    anyMask = __ballot(acc != 0) != 0ull;
  }

  const __bf16* qp = Q + ((size_t)bh * NT + q0 + ql) * 64 + hi * 8;
  bf16x8 qb[4];
#pragma unroll
  for (int kk = 0; kk < 4; kk++) qb[kk] = *reinterpret_cast<const bf16x8*>(qp + kk * 16);

  f32x16 O0 = zero16(), O1 = zero16(), Ol = zero16();
  const __bf16 one1 = (__bf16)1.f;
  const bf16x8 onesv = {one1, one1, one1, one1, one1, one1, one1, one1};

  char* Kb0 = smem;
  char* Kb1 = smem + 8192;
  char* Vb0 = smem + 16384;
  char* Vb1 = smem + 24576;
  const int r8 = lane >> 3, ch = lane & 7;
  const int swch = ch ^ r8;
  const int qlm = ql & 7;

  const char* kbB = (const char*)kb + (w * 16 + r8) * 128 + swch * 16;
  const char* vbB = (const char*)vb + (w * 16 + r8) * 4096 + swch * 16;
  char* ldk0 = Kb0 + w * 2048 + lane * 16;
  char* ldk1 = Kb1 + w * 2048 + lane * 16;
  char* ldv0 = Vb0 + w * 2048 + lane * 16;
  char* ldv1 = Vb1 + w * 2048 + lane * 16;

  load_lds16(kbB, ldk0); load_lds16(kbB + 1024, ldk0 + 1024);
  load_lds16(vbB, ldv0); load_lds16(vbB + 32768, ldv0 + 1024);
  load_lds16(kbB + 8192, ldk1); load_lds16(kbB + 9216, ldk1 + 1024);
  load_lds16(vbB + 128, ldv1); load_lds16(vbB + 32896, ldv1 + 1024);
  const char* kgA = kbB + 16384; const char* vgA = vbB + 256;
  const char* kgB = kbB + 24576; const char* vgB = vbB + 384;

#define COMPUTE(KC, VC, S0)                                                                     \
  do {                                                                                          \
    asm volatile("" ::: "memory");                                                              \
    f32x16 st0 = zero16(), st1 = zero16();                                                      \
    __builtin_amdgcn_s_setprio(1);                                                              \
    _Pragma("unroll") for (int kk = 0; kk < 4; kk++) {                                          \
      bf16x8 ka = *reinterpret_cast<const bf16x8*>((KC) + ql * 128 + (((2 * kk + hi) ^ qlm) << 4)); \
      st0 = __builtin_amdgcn_mfma_f32_32x32x16_bf16(ka, qb[kk], st0, 0, 0, 0);                  \
    }                                                                                           \
    _Pragma("unroll") for (int kk = 0; kk < 4; kk++) {                                          \
      bf16x8 ka = *reinterpret_cast<const bf16x8*>((KC) + (32 + ql) * 128 + (((2 * kk + hi) ^ qlm) << 4)); \
      st1 = __builtin_amdgcn_mfma_f32_32x32x16_bf16(ka, qb[kk], st1, 0, 0, 0);                  \
    }                                                                                           \
    __builtin_amdgcn_s_setprio(0);                                                              \
    if (anyMask) {                                                                              \
      _Pragma("unroll") for (int r = 0; r < 16; ++r) {                                          \
        int s = (r & 3) + 4 * hi + 8 * (r >> 2);                                                \
        if (mb[(S0) + s]) st0[r] = -1e30f;                                                      \
        if (mb[(S0) + 32 + s]) st1[r] = -1e30f;                                                 \
      }                                                                                         \
    }                                                                                           \
    float p[32];                                                                                \
    _Pragma("unroll") for (int r = 0; r < 16; ++r) {                                            \
      p[r] = __builtin_amdgcn_exp2f(st0[r]);                                                    \
      p[16 + r] = __builtin_amdgcn_exp2f(st1[r]);                                               \
    }                                                                                           \
    unsigned wv[16];                                                                            \
    _Pragma("unroll") for (int g = 0; g < 4; ++g) {                                             \
      unsigned A1 = pkbf(p[g * 8 + 0], p[g * 8 + 1]);                                           \
      unsigned A2 = pkbf(p[g * 8 + 2], p[g * 8 + 3]);                                           \
      unsigned A3 = pkbf(p[g * 8 + 4], p[g * 8 + 5]);                                           \
      unsigned A4 = pkbf(p[g * 8 + 6], p[g * 8 + 7]);                                           \
      asm("v_permlane32_swap_b32 %0, %1" : "+v"(A1), "+v"(A3));                                 \
      asm("v_permlane32_swap_b32 %0, %1" : "+v"(A2), "+v"(A4));                                 \
      wv[g * 4 + 0] = A1; wv[g * 4 + 1] = A2; wv[g * 4 + 2] = A3; wv[g * 4 + 3] = A4;           \
    }                                                                                           \
    __builtin_amdgcn_s_setprio(1);                                                              \
    _Pragma("unroll") for (int g = 0; g < 4; ++g) {                                             \
      union { unsigned u[4]; bf16x8 v; } pu;                                                    \
      pu.u[0] = wv[g * 4 + 0]; pu.u[1] = wv[g * 4 + 1];                                         \
      pu.u[2] = wv[g * 4 + 2]; pu.u[3] = wv[g * 4 + 3];                                         \
      bf16x8 pbv = pu.v;                                                                        \
      bf16x8 va0 = *reinterpret_cast<const bf16x8*>((VC) + ql * 128 + (((2 * g + hi) ^ qlm) << 4)); \
      O0 = __builtin_amdgcn_mfma_f32_32x32x16_bf16(va0, pbv, O0, 0, 0, 0);                      \
      bf16x8 va1 = *reinterpret_cast<const bf16x8*>((VC) + (32 + ql) * 128 + (((2 * g + hi) ^ qlm) << 4)); \
      O1 = __builtin_amdgcn_mfma_f32_32x32x16_bf16(va1, pbv, O1, 0, 0, 0);                      \
      Ol = __builtin_amdgcn_mfma_f32_32x32x16_bf16(onesv, pbv, Ol, 0, 0, 0);                    \
    }                                                                                           \
    __builtin_amdgcn_s_setprio(0);                                                              \
    asm volatile("" ::: "memory");                                                              \
  } while (0)

  for (int tt = 0; tt < 16; ++tt) {
    asm volatile("s_waitcnt vmcnt(4)" ::: "memory");
    __builtin_amdgcn_s_barrier();
    COMPUTE(Kb0, Vb0, tt * 128);
    __builtin_amdgcn_s_barrier();
    if (tt < 15) {
      load_lds16(kgA, ldk0); load_lds16(kgA + 1024, ldk0 + 1024);
      load_lds16(vgA, ldv0); load_lds16(vgA + 32768, ldv0 + 1024);
      kgA += 16384; vgA += 256;
    }
    if (tt == 15) { asm volatile("s_waitcnt vmcnt(0)" ::: "memory"); }
    else         { asm volatile("s_waitcnt vmcnt(4)" ::: "memory"); }
    __builtin_amdgcn_s_barrier();
    COMPUTE(Kb1, Vb1, tt * 128 + 64);
    __builtin_amdgcn_s_barrier();
    if (tt < 15) {
      load_lds16(kgB, ldk1); load_lds16(kgB + 1024, ldk1 + 1024);
      load_lds16(vgB, ldv1); load_lds16(vgB + 32768, ldv1 + 1024);
      kgB += 16384; vgB += 256;
    }
  }
#undef COMPUTE

  asm volatile("" ::: "memory");
  __builtin_amdgcn_s_barrier();
  float* tb = (float*)(smem + w * 8192);
  const int esw = (ql & 7) << 2;
  float inv = 1.0f / Ol[0];
#pragma unroll
  for (int r = 0; r < 16; ++r) {
    int drow = (r & 3) + 8 * (r >> 2) + 4 * hi;
    tb[ql * 64 + (drow ^ esw)] = O0[r] * inv;
    tb[ql * 64 + ((32 + drow) ^ esw)] = O1[r] * inv;
  }
  float* op = out + ((size_t)b * NT + q0 + ql) * 1024 + h * 64 + hi * 32;
#pragma unroll
  for (int jj = 0; jj < 8; ++jj) {
    const float* rp = tb + ql * 64 + ((hi * 32 + jj * 4) ^ esw);
    float4 v = {rp[0], rp[1], rp[2], rp[3]};
    *reinterpret_cast<float4*>(op + jj * 4) = v;
  }
}

extern "C" void kernel_launch(void* const* d_in, const int* in_sizes, int n_in,
                              void* d_out, int out_size, void* d_ws, size_t ws_size,
                              hipStream_t stream) {
  const float* query = (const float*)d_in[0];
  const float* key   = (const float*)d_in[1];
  const float* value = (const float*)d_in[2];
  const unsigned char* mask = (const unsigned char*)d_in[3];
  const float* Wq = (const float*)d_in[4];
  const float* bq = (const float*)d_in[5];
  const float* Wk = (const float*)d_in[6];
  const float* bk = (const float*)d_in[7];
  float* out = (float*)d_out;

  char* ws = (char*)d_ws;
  const size_t MB16 = 16777216;
  __bf16* qh = (__bf16*)(ws);
  __bf16* kh = (__bf16*)(ws + MB16);
  __bf16* vt = (__bf16*)(ws + 2 * MB16);
  __bf16* wq = (__bf16*)(ws + 3 * MB16);
  __bf16* wk = (__bf16*)(ws + 3 * MB16 + 2097152);

  // 1) W conversion (q/k conversion fused into proj)
  hipLaunchKernelGGL(cvtw_kernel, dim3(2048), dim3(256), 0, stream, Wq, Wk, wq, wk);

  // 2) both projections (R11 structure + order-pinned waits) + V transpose
  hipLaunchKernelGGL(projvt_kernel, dim3(3072), dim3(256), 0, stream,
                     query, key, wq, wk, bq, bk, qh, kh, value, vt);

  // 3) attention
  hipLaunchKernelGGL(attn_kernel, dim3(1024), dim3(256), 0, stream, qh, kh, vt, mask, out);
}

// Round 16
// 147.760 us; speedup vs baseline: 1.0661x; 1.0661x over previous
//
#include <hip/hip_runtime.h>
#include <hip/hip_bf16.h>

#define NB 4
#define NT 2048
#define NS 2048
#define ND 1024
#define NH 16

typedef __attribute__((ext_vector_type(8))) __bf16 bf16x8;
typedef __attribute__((ext_vector_type(4))) __bf16 bf16x4;
typedef __attribute__((ext_vector_type(2))) __bf16 bf16x2;
typedef __attribute__((ext_vector_type(4))) float f32x4;
typedef __attribute__((ext_vector_type(16))) float f32x16;

__device__ __forceinline__ void load_lds16(const void* g, void* l) {
  __builtin_amdgcn_global_load_lds(
      (const __attribute__((address_space(1))) unsigned int*)g,
      (__attribute__((address_space(3))) unsigned int*)l, 16, 0, 0);
}

__device__ __forceinline__ unsigned pkbf(float lo, float hi) {
  bf16x2 t = {(__bf16)lo, (__bf16)hi};
  return __builtin_bit_cast(unsigned, t);
}

__device__ __forceinline__ f32x16 zero16() {
  f32x16 z;
#pragma unroll
  for (int i = 0; i < 16; i++) z[i] = 0.f;
  return z;
}

// ---------------- Wq/Wk fp32 -> bf16 (small, 8MB read) ----------------
__global__ __launch_bounds__(256) void cvtw_kernel(const float* __restrict__ wq,
                                                   const float* __restrict__ wk,
                                                   __bf16* __restrict__ owq,
                                                   __bf16* __restrict__ owk) {
  int i = blockIdx.x * 256 + threadIdx.x;  // 0..524287 float4s
  const float* src = (i < 262144) ? wq : wk;
  __bf16* dst = (i < 262144) ? owq : owk;
  int off = i & 262143;
  float4 v = reinterpret_cast<const float4*>(src)[off];
  bf16x4 o = {(__bf16)v.x, (__bf16)v.y, (__bf16)v.z, (__bf16)v.w};
  reinterpret_cast<bf16x4*>(dst)[off] = o;
}

// ---------------- merged proj (blocks 0..1023) + V transpose (1024..3071) --------------
// proj: out = relu(X_f32 @ W_bf16^T + b) * scale  (R11 known-good configuration).
// A: fp32 reg-staged 1-deep. W: bf16 gload_lds, single Bs buffer.
// Per-iter source order: cvt_write(A regs->LDS), B gload_lds x2, A-prefetch x4,
// vmcnt(4) lgkmcnt(0): drains B (2 oldest of 6) and the ds_writes, leaves the
// 4 A-prefetch loads in flight across the MFMA phase.
__global__ __launch_bounds__(256) void projvt_kernel(const float* __restrict__ query,
                                                     const float* __restrict__ key,
                                                     const __bf16* __restrict__ Wqb,
                                                     const __bf16* __restrict__ Wkb,
                                                     const float* __restrict__ bq,
                                                     const float* __restrict__ bk,
                                                     __bf16* __restrict__ outq,
                                                     __bf16* __restrict__ outk,
                                                     const float* __restrict__ value,
                                                     __bf16* __restrict__ vt) {
  __shared__ __align__(16) char psm[16896];  // proj: As 8K + Bs 8K; vt: 64x65 f32
  const int tid = threadIdx.x;

  if (blockIdx.x >= 1024) {
    // ---- vt path: value[B,S,1024] -> vt[B*H][64][S]
    float (*tile)[65] = (float(*)[65])psm;
    int bid = blockIdx.x - 1024;
    int st = bid & 31;
    int bh = bid >> 5;
    int b = bh >> 4, h = bh & 15;
    int s0 = st * 64;
#pragma unroll
    for (int rr = 0; rr < 16; rr++) {
      int idx = rr * 256 + tid;
      int r = idx >> 6, c = idx & 63;
      tile[r][c] = value[(size_t)(b * NS + s0 + r) * 1024 + h * 64 + c];
    }
    __syncthreads();
    int d0 = tid >> 5;
    int sp = (tid & 31) * 2;
#pragma unroll
    for (int rr = 0; rr < 8; rr++) {
      int d = rr * 8 + d0;
      bf16x2 o = {(__bf16)tile[sp][d], (__bf16)tile[sp + 1][d]};
      *reinterpret_cast<bf16x2*>(vt + ((size_t)bh * 64 + d) * NS + s0 + sp) = o;
    }
    return;
  }

  // ---- proj path
  __bf16* As = (__bf16*)psm;
  __bf16* Bs = (__bf16*)(psm + 8192);
  const int z = blockIdx.x >> 9;
  const float* A32 = z ? key : query;
  const __bf16* W = z ? Wkb : Wqb;
  const float* bias = z ? bk : bq;
  __bf16* out = z ? outk : outq;
  const float scale = z ? 1.0f : 0.18033688f;  // q: 0.125 * log2(e)

  const int w = tid >> 6, lane = tid & 63;
  int orig = blockIdx.x & 511;
  int wgid = (orig & 7) * 64 + (orig >> 3);  // XCD swizzle
  const int m0 = (wgid >> 3) * 128;
  const int n0 = (wgid & 7) * 128;
  const int wm = w >> 1, wn = w & 1;

  f32x4 acc[4][4];
#pragma unroll
  for (int i = 0; i < 4; i++)
#pragma unroll
    for (int j = 0; j < 4; j++) acc[i][j] = (f32x4){0.f, 0.f, 0.f, 0.f};

  const int arow = lane >> 2;       // 0..15
  const int acol = (lane & 3) * 8;  // 0,8,16,24 (elems)
  const int fr = lane & 15, fg = lane >> 4;

  const float* ap0 = A32 + (size_t)(m0 + w * 32 + arow) * 1024 + acol;
  const float* ap1 = ap0 + 16 * 1024;
  float4 a00 = *(const float4*)(ap0), a01 = *(const float4*)(ap0 + 4);
  float4 a10 = *(const float4*)(ap1), a11 = *(const float4*)(ap1 + 4);

  for (int kt = 0; kt < 1024; kt += 32) {
    // cvt current A regs -> LDS (LDS free: barrier2 of prev iter)
    {
      bf16x8 c0 = {(__bf16)a00.x, (__bf16)a00.y, (__bf16)a00.z, (__bf16)a00.w,
                   (__bf16)a01.x, (__bf16)a01.y, (__bf16)a01.z, (__bf16)a01.w};
      bf16x8 c1 = {(__bf16)a10.x, (__bf16)a10.y, (__bf16)a10.z, (__bf16)a10.w,
                   (__bf16)a11.x, (__bf16)a11.y, (__bf16)a11.z, (__bf16)a11.w};
      *reinterpret_cast<bf16x8*>(&As[(w * 32 + arow) * 32 + acol]) = c0;
      *reinterpret_cast<bf16x8*>(&As[(w * 32 + 16 + arow) * 32 + acol]) = c1;
    }
    // B: direct global->LDS (2 ops)
#pragma unroll
    for (int i = 0; i < 2; i++) {
      int r = w * 32 + i * 16 + arow;
      load_lds16(W + (size_t)(n0 + r) * 1024 + kt + acol, &Bs[(w * 32 + i * 16) * 32]);
    }
    // prefetch next A tile into regs (4 loads stay in flight across barrier)
    if (kt < 992) {
      a00 = *(const float4*)(ap0 + kt + 32);
      a01 = *(const float4*)(ap0 + kt + 36);
      a10 = *(const float4*)(ap1 + kt + 32);
      a11 = *(const float4*)(ap1 + kt + 36);
      asm volatile("s_waitcnt vmcnt(4) lgkmcnt(0)" ::: "memory");
    } else {
      asm volatile("s_waitcnt vmcnt(0) lgkmcnt(0)" ::: "memory");
    }
    __builtin_amdgcn_s_barrier();
    asm volatile("" ::: "memory");

    bf16x8 af[4], bfr[4];
#pragma unroll
    for (int mi = 0; mi < 4; mi++)
      af[mi] = *reinterpret_cast<const bf16x8*>(&As[(wm * 64 + mi * 16 + fr) * 32 + fg * 8]);
#pragma unroll
    for (int ni = 0; ni < 4; ni++)
      bfr[ni] = *reinterpret_cast<const bf16x8*>(&Bs[(wn * 64 + ni * 16 + fr) * 32 + fg * 8]);
#pragma unroll
    for (int mi = 0; mi < 4; mi++)
#pragma unroll
      for (int ni = 0; ni < 4; ni++)
        acc[mi][ni] = __builtin_amdgcn_mfma_f32_16x16x32_bf16(af[mi], bfr[ni], acc[mi][ni], 0, 0, 0);

    asm volatile("" ::: "memory");
    __builtin_amdgcn_s_barrier();
  }

#pragma unroll
  for (int ni = 0; ni < 4; ni++) {
    int n = n0 + wn * 64 + ni * 16 + fr;
    float bv = bias[n];
    int h = n >> 6, d = n & 63;
#pragma unroll
    for (int mi = 0; mi < 4; mi++) {
#pragma unroll
      for (int i = 0; i < 4; i++) {
        int m = m0 + wm * 64 + mi * 16 + fg * 4 + i;
        int b = m >> 11, t = m & 2047;
        float v = acc[mi][ni][i] + bv;
        v = fmaxf(v, 0.f) * scale;
        out[(size_t)((b * NH + h) * NT + t) * 64 + d] = (__bf16)v;
      }
    }
  }
}

// ---------------- flash attention (4 waves x 32 q-rows) -- proven best (86.4us) --------
__global__ __launch_bounds__(256, 4) void attn_kernel(const __bf16* __restrict__ Q,
                                                      const __bf16* __restrict__ K,
                                                      const __bf16* __restrict__ Vt,
                                                      const unsigned char* __restrict__ mask,
                                                      float* __restrict__ out) {
  __shared__ __align__(16) char smem[32768];
  const int tid = threadIdx.x;
  const int w = tid >> 6, lane = tid & 63;
  int orig = blockIdx.x;
  int wgid = (orig & 7) * 128 + (orig >> 3);  // XCD swizzle: 8 bh per XCD
  const int qt = wgid & 15, bh = wgid >> 4;
  const int b = bh >> 4, h = bh & 15;
  const int q0 = qt * 128 + w * 32;
  const int ql = lane & 31, hi = lane >> 5;

  const __bf16* kb = K + (size_t)bh * NS * 64;
  const __bf16* vb = Vt + (size_t)bh * 64 * NS;
  const unsigned char* mb = mask + (size_t)b * NS;

  bool anyMask;
  {
    const uint4* mp4 = reinterpret_cast<const uint4*>(mb);
    uint4 a = mp4[lane * 2], c = mp4[lane * 2 + 1];
    unsigned acc = a.x | a.y | a.z | a.w | c.x | c.y | c.z | c.w;
    anyMask = __ballot(acc != 0) != 0ull;
  }

  const __bf16* qp = Q + ((size_t)bh * NT + q0 + ql) * 64 + hi * 8;
  bf16x8 qb[4];
#pragma unroll
  for (int kk = 0; kk < 4; kk++) qb[kk] = *reinterpret_cast<const bf16x8*>(qp + kk * 16);

  f32x16 O0 = zero16(), O1 = zero16(), Ol = zero16();
  const __bf16 one1 = (__bf16)1.f;
  const bf16x8 onesv = {one1, one1, one1, one1, one1, one1, one1, one1};

  char* Kb0 = smem;
  char* Kb1 = smem + 8192;
  char* Vb0 = smem + 16384;
  char* Vb1 = smem + 24576;
  const int r8 = lane >> 3, ch = lane & 7;
  const int swch = ch ^ r8;
  const int qlm = ql & 7;

  const char* kbB = (const char*)kb + (w * 16 + r8) * 128 + swch * 16;
  const char* vbB = (const char*)vb + (w * 16 + r8) * 4096 + swch * 16;
  char* ldk0 = Kb0 + w * 2048 + lane * 16;
  char* ldk1 = Kb1 + w * 2048 + lane * 16;
  char* ldv0 = Vb0 + w * 2048 + lane * 16;
  char* ldv1 = Vb1 + w * 2048 + lane * 16;

  load_lds16(kbB, ldk0); load_lds16(kbB + 1024, ldk0 + 1024);
  load_lds16(vbB, ldv0); load_lds16(vbB + 32768, ldv0 + 1024);
  load_lds16(kbB + 8192, ldk1); load_lds16(kbB + 9216, ldk1 + 1024);
  load_lds16(vbB + 128, ldv1); load_lds16(vbB + 32896, ldv1 + 1024);
  const char* kgA = kbB + 16384; const char* vgA = vbB + 256;
  const char* kgB = kbB + 24576; const char* vgB = vbB + 384;

#define COMPUTE(KC, VC, S0)                                                                     \
  do {                                                                                          \
    asm volatile("" ::: "memory");                                                              \
    f32x16 st0 = zero16(), st1 = zero16();                                                      \
    __builtin_amdgcn_s_setprio(1);                                                              \
    _Pragma("unroll") for (int kk = 0; kk < 4; kk++) {                                          \
      bf16x8 ka = *reinterpret_cast<const bf16x8*>((KC) + ql * 128 + (((2 * kk + hi) ^ qlm) << 4)); \
      st0 = __builtin_amdgcn_mfma_f32_32x32x16_bf16(ka, qb[kk], st0, 0, 0, 0);                  \
    }                                                                                           \
    _Pragma("unroll") for (int kk = 0; kk < 4; kk++) {                                          \
      bf16x8 ka = *reinterpret_cast<const bf16x8*>((KC) + (32 + ql) * 128 + (((2 * kk + hi) ^ qlm) << 4)); \
      st1 = __builtin_amdgcn_mfma_f32_32x32x16_bf16(ka, qb[kk], st1, 0, 0, 0);                  \
    }                                                                                           \
    __builtin_amdgcn_s_setprio(0);                                                              \
    if (anyMask) {                                                                              \
      _Pragma("unroll") for (int r = 0; r < 16; ++r) {                                          \
        int s = (r & 3) + 4 * hi + 8 * (r >> 2);                                                \
        if (mb[(S0) + s]) st0[r] = -1e30f;                                                      \
        if (mb[(S0) + 32 + s]) st1[r] = -1e30f;                                                 \
      }                                                                                         \
    }                                                                                           \
    float p[32];                                                                                \
    _Pragma("unroll") for (int r = 0; r < 16; ++r) {                                            \
      p[r] = __builtin_amdgcn_exp2f(st0[r]);                                                    \
      p[16 + r] = __builtin_amdgcn_exp2f(st1[r]);                                               \
    }                                                                                           \
    unsigned wv[16];                                                                            \
    _Pragma("unroll") for (int g = 0; g < 4; ++g) {                                             \
      unsigned A1 = pkbf(p[g * 8 + 0], p[g * 8 + 1]);                                           \
      unsigned A2 = pkbf(p[g * 8 + 2], p[g * 8 + 3]);                                           \
      unsigned A3 = pkbf(p[g * 8 + 4], p[g * 8 + 5]);                                           \
      unsigned A4 = pkbf(p[g * 8 + 6], p[g * 8 + 7]);                                           \
      asm("v_permlane32_swap_b32 %0, %1" : "+v"(A1), "+v"(A3));                                 \
      asm("v_permlane32_swap_b32 %0, %1" : "+v"(A2), "+v"(A4));                                 \
      wv[g * 4 + 0] = A1; wv[g * 4 + 1] = A2; wv[g * 4 + 2] = A3; wv[g * 4 + 3] = A4;           \
    }                                                                                           \
    __builtin_amdgcn_s_setprio(1);                                                              \
    _Pragma("unroll") for (int g = 0; g < 4; ++g) {                                             \
      union { unsigned u[4]; bf16x8 v; } pu;                                                    \
      pu.u[0] = wv[g * 4 + 0]; pu.u[1] = wv[g * 4 + 1];                                         \
      pu.u[2] = wv[g * 4 + 2]; pu.u[3] = wv[g * 4 + 3];                                         \
      bf16x8 pbv = pu.v;                                                                        \
      bf16x8 va0 = *reinterpret_cast<const bf16x8*>((VC) + ql * 128 + (((2 * g + hi) ^ qlm) << 4)); \
      O0 = __builtin_amdgcn_mfma_f32_32x32x16_bf16(va0, pbv, O0, 0, 0, 0);                      \
      bf16x8 va1 = *reinterpret_cast<const bf16x8*>((VC) + (32 + ql) * 128 + (((2 * g + hi) ^ qlm) << 4)); \
      O1 = __builtin_amdgcn_mfma_f32_32x32x16_bf16(va1, pbv, O1, 0, 0, 0);                      \
      Ol = __builtin_amdgcn_mfma_f32_32x32x16_bf16(onesv, pbv, Ol, 0, 0, 0);                    \
    }                                                                                           \
    __builtin_amdgcn_s_setprio(0);                                                              \
    asm volatile("" ::: "memory");                                                              \
  } while (0)

  for (int tt = 0; tt < 16; ++tt) {
    asm volatile("s_waitcnt vmcnt(4)" ::: "memory");
    __builtin_amdgcn_s_barrier();
    COMPUTE(Kb0, Vb0, tt * 128);
    __builtin_amdgcn_s_barrier();
    if (tt < 15) {
      load_lds16(kgA, ldk0); load_lds16(kgA + 1024, ldk0 + 1024);
      load_lds16(vgA, ldv0); load_lds16(vgA + 32768, ldv0 + 1024);
      kgA += 16384; vgA += 256;
    }
    if (tt == 15) { asm volatile("s_waitcnt vmcnt(0)" ::: "memory"); }
    else         { asm volatile("s_waitcnt vmcnt(4)" ::: "memory"); }
    __builtin_amdgcn_s_barrier();
    COMPUTE(Kb1, Vb1, tt * 128 + 64);
    __builtin_amdgcn_s_barrier();
    if (tt < 15) {
      load_lds16(kgB, ldk1); load_lds16(kgB + 1024, ldk1 + 1024);
      load_lds16(vgB, ldv1); load_lds16(vgB + 32768, ldv1 + 1024);
      kgB += 16384; vgB += 256;
    }
  }
#undef COMPUTE

  asm volatile("" ::: "memory");
  __builtin_amdgcn_s_barrier();
  float* tb = (float*)(smem + w * 8192);
  const int esw = (ql & 7) << 2;
  float inv = 1.0f / Ol[0];
#pragma unroll
  for (int r = 0; r < 16; ++r) {
    int drow = (r & 3) + 8 * (r >> 2) + 4 * hi;
    tb[ql * 64 + (drow ^ esw)] = O0[r] * inv;
    tb[ql * 64 + ((32 + drow) ^ esw)] = O1[r] * inv;
  }
  float* op = out + ((size_t)b * NT + q0 + ql) * 1024 + h * 64 + hi * 32;
#pragma unroll
  for (int jj = 0; jj < 8; ++jj) {
    const float* rp = tb + ql * 64 + ((hi * 32 + jj * 4) ^ esw);
    float4 v = {rp[0], rp[1], rp[2], rp[3]};
    *reinterpret_cast<float4*>(op + jj * 4) = v;
  }
}

extern "C" void kernel_launch(void* const* d_in, const int* in_sizes, int n_in,
                              void* d_out, int out_size, void* d_ws, size_t ws_size,
                              hipStream_t stream) {
  const float* query = (const float*)d_in[0];
  const float* key   = (const float*)d_in[1];
  const float* value = (const float*)d_in[2];
  const unsigned char* mask = (const unsigned char*)d_in[3];
  const float* Wq = (const float*)d_in[4];
  const float* bq = (const float*)d_in[5];
  const float* Wk = (const float*)d_in[6];
  const float* bk = (const float*)d_in[7];
  float* out = (float*)d_out;

  char* ws = (char*)d_ws;
  const size_t MB16 = 16777216;
  __bf16* qh = (__bf16*)(ws);
  __bf16* kh = (__bf16*)(ws + MB16);
  __bf16* vt = (__bf16*)(ws + 2 * MB16);
  __bf16* wq = (__bf16*)(ws + 3 * MB16);
  __bf16* wk = (__bf16*)(ws + 3 * MB16 + 2097152);

  // 1) W conversion (q/k conversion fused into proj)
  hipLaunchKernelGGL(cvtw_kernel, dim3(2048), dim3(256), 0, stream, Wq, Wk, wq, wk);

  // 2) both projections (R11 configuration) + V transpose
  hipLaunchKernelGGL(projvt_kernel, dim3(3072), dim3(256), 0, stream,
                     query, key, wq, wk, bq, bk, qh, kh, value, vt);

  // 3) attention
  hipLaunchKernelGGL(attn_kernel, dim3(1024), dim3(256), 0, stream, qh, kh, vt, mask, out);
}